// Round 3
// baseline (462.404 us; speedup 1.0000x reference)
//
#include <hip/hip_runtime.h>
#include <math.h>

// Problem constants (fixed by reference)
#define N_TOT 16384
#define DIM   256
#define KCB   4096

typedef __attribute__((ext_vector_type(8)))  short s8v;   // 8 bf16 = 4 VGPR
typedef __attribute__((ext_vector_type(16))) float f16v;  // MFMA 32x32 accumulator

// ---------------- ws layout (bytes) ----------------
// [0)       cbn    : 4096 f32 (||e_k||^2)
// [16384)   counts : 4096 f32
// [32768)   loss   : 1 f32 (+pad to 32832)
// [32832)   packed : 16384 u64 (argmin merge)        -> 163904
// [163904)  cbH    : 4096*256 ushort (2 MB)
// [2261056) cbL    : 4096*256 ushort (2 MB)          -> 4358208
// [4358208) guard  : 128 KB (cross-kt prefetch overrun)
#define CBH_OFF   163904
#define PK_OFF    32832
#define WS_NEED   4489280ull
#define ZERO_W    36880   // words from ws[4096] to byte 163904

__global__ void zero_ws_k(float* __restrict__ ws, int nw) {
  int i = blockIdx.x * 256 + threadIdx.x;
  if (i < nw) ws[KCB + i] = 0.0f;   // counts + loss + packed
}

// codebook prep: norms + hi/lo bf16 split. one wave per row, 4 floats/lane.
__global__ void cb_prep_k(const float* __restrict__ cb, float* __restrict__ ws) {
  int row  = blockIdx.x * 4 + (threadIdx.x >> 6);
  int lane = threadIdx.x & 63;
  ushort* cbH = (ushort*)((char*)ws + CBH_OFF);
  ushort* cbL = cbH + (size_t)KCB * DIM;
  float4 v = *(const float4*)(cb + (size_t)row * DIM + lane * 4);
  float xs[4] = {v.x, v.y, v.z, v.w};
  unsigned h[4], l[4];
  float s = 0.0f;
  #pragma unroll
  for (int j = 0; j < 4; ++j) {
    s += xs[j] * xs[j];
    unsigned xb = __float_as_uint(xs[j]);
    unsigned hb = xb & 0xFFFF0000u;
    float lf = xs[j] - __uint_as_float(hb);   // exact
    h[j] = hb >> 16;
    l[j] = __float_as_uint(lf) >> 16;          // truncate
  }
  *(uint2*)&cbH[(size_t)row * DIM + lane * 4] = make_uint2(h[0] | (h[1] << 16), h[2] | (h[3] << 16));
  *(uint2*)&cbL[(size_t)row * DIM + lane * 4] = make_uint2(l[0] | (l[1] << 16), l[2] | (l[3] << 16));
  #pragma unroll
  for (int off = 32; off > 0; off >>= 1) s += __shfl_down(s, off, 64);
  if (lane == 0) ws[row] = s;
}

// ---------------- main MFMA kernel ----------------
// 1024 blocks x 256 threads (4 waves). Block = 64 rows x 1024 cols
// (col-quarter = blockIdx&3 -> XCD %8 round-robin gives each XCD ONE 1MB
// codebook quarter -> L2-resident B stream). 8 kt supertiles of 128 cols
// (4 waves x 32). A (hi+lo bf16) in LDS, padded pitch; B streamed
// global->regs with a 3-deep rolling 4-slot prefetch whose offsets are
// static across kt boundaries (no per-kt bubble).
#define BM 64
#define APITCH 264   // 256 + 8 ushort pad = 528 B row pitch

__global__ __launch_bounds__(256, 2)
void vq_mfma_k(const float* __restrict__ ze, float* __restrict__ ws) {
  __shared__ ushort AhS[BM * APITCH];   // 33 KB
  __shared__ ushort AlS[BM * APITCH];   // 33 KB
  __shared__ float  redS[BM * 4];
  __shared__ int    redI[BM * 4];

  const int t  = threadIdx.x;
  const int m0 = (blockIdx.x >> 2) * BM;
  const int cq = blockIdx.x & 3;        // col quarter (XCD-affine)

  const float* cbn = ws;
  unsigned long long* pk = (unsigned long long*)((char*)ws + PK_OFF);
  const ushort* cbH = (const ushort*)((const char*)ws + CBH_OFF);
  const ushort* cbL = cbH + (size_t)KCB * DIM;

  // ---- stage A: fp32 ze rows -> bf16 h/l in LDS ----
  {
    int m  = t >> 2;            // 0..63
    int c0 = t & 3;
    const float* src = ze + (size_t)(m0 + m) * DIM;
    #pragma unroll
    for (int i = 0; i < 8; ++i) {
      int c = c0 + 4 * i;       // chunk of 8 floats
      float4 x0 = *(const float4*)(src + c * 8);
      float4 x1 = *(const float4*)(src + c * 8 + 4);
      float xs[8] = {x0.x, x0.y, x0.z, x0.w, x1.x, x1.y, x1.z, x1.w};
      unsigned h[8], l[8];
      #pragma unroll
      for (int j = 0; j < 8; ++j) {
        unsigned xb = __float_as_uint(xs[j]);
        unsigned hb = xb & 0xFFFF0000u;
        float lf = xs[j] - __uint_as_float(hb);
        h[j] = hb >> 16;
        l[j] = __float_as_uint(lf) >> 16;
      }
      *(uint4*)&AhS[m * APITCH + c * 8] =
          make_uint4(h[0] | (h[1] << 16), h[2] | (h[3] << 16), h[4] | (h[5] << 16), h[6] | (h[7] << 16));
      *(uint4*)&AlS[m * APITCH + c * 8] =
          make_uint4(l[0] | (l[1] << 16), l[2] | (l[3] << 16), l[4] | (l[5] << 16), l[6] | (l[7] << 16));
    }
  }
  __syncthreads();

  const int lane = t & 63;
  const int w    = t >> 6;      // wave 0..3
  const int ln31 = lane & 31;
  const int hl   = lane >> 5;

  const ushort* paH0 = AhS + ln31 * APITCH + hl * 8;
  const ushort* paH1 = AhS + (ln31 + 32) * APITCH + hl * 8;
  const ushort* paL0 = AlS + ln31 * APITCH + hl * 8;
  const ushort* paL1 = AlS + (ln31 + 32) * APITCH + hl * 8;

  // B base (s8v units): col0 = cq*1024 + w*32 + ln31
  const int col0 = cq * 1024 + w * 32 + ln31;
  const s8v* pbh = (const s8v*)(cbH + (size_t)col0 * DIM + hl * 8);
  const s8v* pbl = (const s8v*)(cbL + (size_t)col0 * DIM + hl * 8);
  // per-kt advance: 128 cols * 256 dim = 32768 ushorts = 4096 s8v
  #define KT_ADV 4096

  float best[32];
  int   bidx[32];
  #pragma unroll
  for (int i = 0; i < 32; ++i) { best[i] = -1e30f; bidx[i] = 0; }

  // rolling 4-slot, 3-deep prefetch
  s8v bufH[4], bufL[4];
  bufH[0] = pbh[0]; bufL[0] = pbl[0];
  bufH[1] = pbh[2]; bufL[1] = pbl[2];
  bufH[2] = pbh[4]; bufL[2] = pbl[4];

  #pragma unroll 1
  for (int kt = 0; kt < 8; ++kt) {
    const int col = col0 + kt * 128;
    const float half_cv = 0.5f * cbn[col];

    f16v hh0, hh1, xx0, xx1;
    #pragma unroll
    for (int r = 0; r < 16; ++r) { hh0[r] = 0.0f; hh1[r] = 0.0f; xx0[r] = 0.0f; xx1[r] = 0.0f; }

    #pragma unroll
    for (int ks = 0; ks < 16; ++ks) {
      const int s  = ks & 3;
      const int sp = (ks + 3) & 3;
      // prefetch step ks+3 (crosses into kt+1 for ks>=13; static offsets)
      if (ks <= 12) { bufH[sp] = pbh[2 * (ks + 3)];            bufL[sp] = pbl[2 * (ks + 3)]; }
      else          { bufH[sp] = pbh[KT_ADV + 2 * (ks - 13)];  bufL[sp] = pbl[KT_ADV + 2 * (ks - 13)]; }

      s8v ah0 = *(const s8v*)(paH0 + ks * 16);
      s8v ah1 = *(const s8v*)(paH1 + ks * 16);
      s8v al0 = *(const s8v*)(paL0 + ks * 16);
      s8v al1 = *(const s8v*)(paL1 + ks * 16);
      s8v bh = bufH[s], bl = bufL[s];
      xx0 = __builtin_amdgcn_mfma_f32_32x32x16_bf16(ah0, bl, xx0, 0, 0, 0);
      xx1 = __builtin_amdgcn_mfma_f32_32x32x16_bf16(ah1, bl, xx1, 0, 0, 0);
      hh0 = __builtin_amdgcn_mfma_f32_32x32x16_bf16(ah0, bh, hh0, 0, 0, 0);
      hh1 = __builtin_amdgcn_mfma_f32_32x32x16_bf16(ah1, bh, hh1, 0, 0, 0);
      xx0 = __builtin_amdgcn_mfma_f32_32x32x16_bf16(al0, bh, xx0, 0, 0, 0);
      xx1 = __builtin_amdgcn_mfma_f32_32x32x16_bf16(al1, bh, xx1, 0, 0, 0);
    }
    pbh += KT_ADV; pbl += KT_ADV;

    // score = dot - 0.5||e||^2 ; cols ascend with kt => '>' keeps first min
    #pragma unroll
    for (int r = 0; r < 16; ++r) {
      float s0 = hh0[r] + xx0[r] - half_cv;
      float s1 = hh1[r] + xx1[r] - half_cv;
      if (s0 > best[r])      { best[r]      = s0; bidx[r]      = col; }
      if (s1 > best[16 + r]) { best[16 + r] = s1; bidx[16 + r] = col; }
    }
  }

  // ---- cross-lane argmax (32 cols per slot), then block merge, then atomicMax ----
  #pragma unroll
  for (int i = 0; i < 2; ++i) {
    #pragma unroll
    for (int r = 0; r < 16; ++r) {
      float s = best[i * 16 + r];
      int   c = bidx[i * 16 + r];
      #pragma unroll
      for (int mk = 1; mk < 32; mk <<= 1) {
        float os = __shfl_xor(s, mk, 64);
        int   oc = __shfl_xor(c, mk, 64);
        if (os > s || (os == s && oc < c)) { s = os; c = oc; }
      }
      if (ln31 == 0) {
        int row = i * 32 + (r & 3) + 8 * (r >> 2) + 4 * hl;
        redS[row * 4 + w] = s;
        redI[row * 4 + w] = c;
      }
    }
  }
  __syncthreads();

  if (t < BM) {
    float bs = redS[t * 4]; int bi = redI[t * 4];
    #pragma unroll
    for (int j = 1; j < 4; ++j) {
      float s = redS[t * 4 + j]; int c = redI[t * 4 + j];
      if (s > bs || (s == bs && c < bi)) { bs = s; bi = c; }
    }
    unsigned u = __float_as_uint(bs);
    unsigned enc = (u & 0x80000000u) ? ~u : (u | 0x80000000u);
    unsigned long long p = ((unsigned long long)enc << 32) | (unsigned)(KCB - 1 - bi);
    atomicMax(&pk[m0 + t], p);
  }
}

// ---- gather: indices out, counts, zq, loss partials ----
__global__ __launch_bounds__(256)
void gather_k(const float* __restrict__ ze, const float* __restrict__ cb,
              float* __restrict__ ws, float* __restrict__ out) {
  __shared__ int sIdx[64];
  const int t  = threadIdx.x;
  const int m0 = blockIdx.x * 64;
  float* counts   = ws + KCB;
  float* loss_sum = ws + 2 * KCB;
  const unsigned long long* pk = (const unsigned long long*)((const char*)ws + PK_OFF);

  if (t < 64) {
    unsigned long long p = pk[m0 + t];
    int col = KCB - 1 - (int)(unsigned)(p & 0xFFFFFFFFull);
    out[m0 + t] = (float)col;
    sIdx[t] = col;
    atomicAdd(&counts[col], 1.0f);
  }
  __syncthreads();

  float* out_zq = out + N_TOT;
  const int w = t >> 6, ln = t & 63;
  float lsum = 0.0f;
  #pragma unroll
  for (int p = 0; p < 16; ++p) {
    int r = w + 4 * p;
    float4 cvv = *(const float4*)(cb + (size_t)sIdx[r] * DIM + ln * 4);
    float4 zv  = *(const float4*)(ze + (size_t)(m0 + r) * DIM + ln * 4);
    *(float4*)(out_zq + (size_t)(m0 + r) * DIM + ln * 4) = cvv;
    float dx = cvv.x - zv.x, dy = cvv.y - zv.y, dz = cvv.z - zv.z, dw = cvv.w - zv.w;
    lsum += dx * dx + dy * dy + dz * dz + dw * dw;
  }
  #pragma unroll
  for (int off = 32; off > 0; off >>= 1) lsum += __shfl_down(lsum, off, 64);
  if (ln == 0) atomicAdd(loss_sum, lsum);
}

// ---------------- fallback (round-1 fp32 path, if ws too small) ----------------
__global__ void cbnorm_k(const float* __restrict__ cb, float* __restrict__ ws) {
  int row  = blockIdx.x * 4 + (threadIdx.x >> 6);
  int lane = threadIdx.x & 63;
  float4 v = *(const float4*)(cb + (size_t)row * DIM + lane * 4);
  float s = v.x*v.x + v.y*v.y + v.z*v.z + v.w*v.w;
  #pragma unroll
  for (int off = 32; off > 0; off >>= 1) s += __shfl_down(s, off, 64);
  if (lane == 0) ws[row] = s;
}

#define FBM 32
#define FBN 64
#define FBD 128
__global__ __launch_bounds__(256, 4)
void vq_main_k(const float* __restrict__ ze, const float* __restrict__ cb,
               float* __restrict__ ws, float* __restrict__ out) {
  __shared__ float As[FBM * FBD];
  __shared__ float Bs[FBN * FBD];
  __shared__ float red_d[FBM * 16];
  __shared__ int   red_i[FBM * 16];
  __shared__ int   sIdx[FBM];

  const int t  = threadIdx.x;
  const int tx = t & 15;
  const int ty = t >> 4;
  const int m0 = blockIdx.x * FBM;

  const float* cbn = ws;
  float* counts    = ws + KCB;
  float* loss_sum  = ws + 2 * KCB;

  float best0 = 1e30f, best1 = 1e30f;
  int   bidx0 = 0,     bidx1 = 0;
  const int sA = ty & 7;
  const int sB = tx & 7;

  for (int kt = 0; kt < KCB / FBN; ++kt) {
    float cbnj[4];
    #pragma unroll
    for (int j = 0; j < 4; ++j) cbnj[j] = cbn[kt * FBN + tx + 16 * j];
    float acc[2][4];
    #pragma unroll
    for (int i = 0; i < 2; ++i)
      #pragma unroll
      for (int j = 0; j < 4; ++j) acc[i][j] = 0.0f;

    for (int dc = 0; dc < DIM / FBD; ++dc) {
      __syncthreads();
      {
        int c  = t & 31;
        int rb = t >> 5;
        #pragma unroll
        for (int p = 0; p < 4; ++p) {
          int r = rb + 8 * p;
          float4 v = *(const float4*)(ze + (size_t)(m0 + r) * DIM + dc * FBD + c * 4);
          *(float4*)&As[r * FBD + ((c ^ (r & 7)) << 2)] = v;
        }
        #pragma unroll
        for (int p = 0; p < 8; ++p) {
          int r = rb + 8 * p;
          float4 v = *(const float4*)(cb + (size_t)(kt * FBN + r) * DIM + dc * FBD + c * 4);
          *(float4*)&Bs[r * FBD + ((c ^ (r & 7)) << 2)] = v;
        }
      }
      __syncthreads();
      #pragma unroll 8
      for (int ds = 0; ds < FBD / 4; ++ds) {
        float4 a0 = *(const float4*)&As[ty * FBD + ((ds ^ sA) << 2)];
        float4 a1 = *(const float4*)&As[(ty + 16) * FBD + ((ds ^ sA) << 2)];
        float4 b[4];
        #pragma unroll
        for (int j = 0; j < 4; ++j)
          b[j] = *(const float4*)&Bs[(tx + 16 * j) * FBD + ((ds ^ sB) << 2)];
        #pragma unroll
        for (int j = 0; j < 4; ++j) {
          acc[0][j] = fmaf(a0.x, b[j].x, acc[0][j]);
          acc[0][j] = fmaf(a0.y, b[j].y, acc[0][j]);
          acc[0][j] = fmaf(a0.z, b[j].z, acc[0][j]);
          acc[0][j] = fmaf(a0.w, b[j].w, acc[0][j]);
          acc[1][j] = fmaf(a1.x, b[j].x, acc[1][j]);
          acc[1][j] = fmaf(a1.y, b[j].y, acc[1][j]);
          acc[1][j] = fmaf(a1.z, b[j].z, acc[1][j]);
          acc[1][j] = fmaf(a1.w, b[j].w, acc[1][j]);
        }
      }
    }
    #pragma unroll
    for (int j = 0; j < 4; ++j) {
      int kg = kt * FBN + tx + 16 * j;
      float d0 = cbnj[j] - 2.0f * acc[0][j];
      float d1 = cbnj[j] - 2.0f * acc[1][j];
      if (d0 < best0) { best0 = d0; bidx0 = kg; }
      if (d1 < best1) { best1 = d1; bidx1 = kg; }
    }
  }

  __syncthreads();
  red_d[ty * 16 + tx] = best0;        red_i[ty * 16 + tx] = bidx0;
  red_d[(ty + 16) * 16 + tx] = best1; red_i[(ty + 16) * 16 + tx] = bidx1;
  __syncthreads();

  if (t < FBM) {
    float bd = red_d[t * 16]; int bi = red_i[t * 16];
    #pragma unroll
    for (int q = 1; q < 16; ++q) {
      float d = red_d[t * 16 + q]; int i2 = red_i[t * 16 + q];
      if (d < bd || (d == bd && i2 < bi)) { bd = d; bi = i2; }
    }
    out[m0 + t] = (float)bi;
    sIdx[t] = bi;
    atomicAdd(&counts[bi], 1.0f);
  }
  __syncthreads();

  float* out_zq = out + N_TOT;
  const int wv = t >> 6, ln = t & 63;
  float lsum = 0.0f;
  #pragma unroll
  for (int p = 0; p < 8; ++p) {
    int r = wv + 4 * p;
    float4 cvv = *(const float4*)(cb + (size_t)sIdx[r] * DIM + ln * 4);
    float4 zv  = *(const float4*)(ze + (size_t)(m0 + r) * DIM + ln * 4);
    *(float4*)(out_zq + (size_t)(m0 + r) * DIM + ln * 4) = cvv;
    float dx = cvv.x - zv.x, dy = cvv.y - zv.y, dz = cvv.z - zv.z, dw = cvv.w - zv.w;
    lsum += dx*dx + dy*dy + dz*dz + dw*dw;
  }
  #pragma unroll
  for (int off = 32; off > 0; off >>= 1) lsum += __shfl_down(lsum, off, 64);
  if (ln == 0) atomicAdd(loss_sum, lsum);
}

__global__ void finalize_k(const float* __restrict__ ws, float* __restrict__ out) {
  __shared__ float red[256];
  int t = threadIdx.x;
  const float* counts = ws + KCB;
  float s = 0.0f;
  for (int k = t; k < KCB; k += 256) {
    float p = counts[k] * 0.1f;
    s += p * logf(p + 1e-10f);
  }
  red[t] = s;
  __syncthreads();
  for (int q = 128; q > 0; q >>= 1) { if (t < q) red[t] += red[t + q]; __syncthreads(); }
  if (t == 0) {
    float loss = ws[2 * KCB] / (float)((size_t)N_TOT * DIM);
    float* o = out + N_TOT + (size_t)N_TOT * DIM;
    o[0] = loss;
    o[1] = loss;
    o[2] = expf(-red[0]);
  }
}

extern "C" void kernel_launch(void* const* d_in, const int* in_sizes, int n_in,
                              void* d_out, int out_size, void* d_ws, size_t ws_size,
                              hipStream_t stream) {
  const float* ze = (const float*)d_in[0];
  const float* cb = (const float*)d_in[1];
  float* out = (float*)d_out;
  float* ws  = (float*)d_ws;

  if (ws_size >= WS_NEED) {
    zero_ws_k<<<(ZERO_W + 255) / 256, 256, 0, stream>>>(ws, ZERO_W);
    cb_prep_k<<<KCB / 4, 256, 0, stream>>>(cb, ws);
    vq_mfma_k<<<(N_TOT / BM) * 4, 256, 0, stream>>>(ze, ws);
    gather_k<<<N_TOT / 64, 256, 0, stream>>>(ze, cb, ws, out);
  } else {
    zero_ws_k<<<(KCB + 1 + 255) / 256, 256, 0, stream>>>(ws, KCB + 1);
    cbnorm_k<<<KCB / 4, 256, 0, stream>>>(cb, ws);
    vq_main_k<<<N_TOT / FBM, 256, 0, stream>>>(ze, cb, ws, out);
  }
  finalize_k<<<1, 256, 0, stream>>>(ws, out);
}

// Round 4
// 193.894 us; speedup vs baseline: 2.3848x; 2.3848x over previous
//
#include <hip/hip_runtime.h>
#include <math.h>

// Problem constants (fixed by reference)
#define N_TOT 16384
#define DIM   256
#define KCB   4096

typedef __attribute__((ext_vector_type(8)))  short s8v;   // 8 bf16 = 4 VGPR
typedef __attribute__((ext_vector_type(16))) float f16v;  // MFMA 32x32 accumulator

// ---------------- ws layout (bytes) ----------------
// [0)      cbn    : 4096 f32 (||e_k||^2)
// [16384)  counts : 4096 f32
// [32768)  loss   : 1 f32 (+pad)
// [32832)  pk     : 16384 u64 (packed argmin merge)   -> 163904
// [163904) cbF    : fragment-linear split codebook, 128 tiles x 32KB = 4MB
//          tile t = cols [32t,32t+32): h 16KB then l 16KB.
//          h ushort idx within tile: ks*512 + khalf*256 + col*8 + j
//          (k = ks*16 + khalf*8 + j)  == LDS order  base + ks*1024 + lane*16
//          with lane = col + 32*khalf  -> global_load_lds is a linear memcpy.
#define PK_OFF   32832
#define CBF_OFF  163904
#define WS_NEED  4358208ull
#define ZERO_W   36880   // f32 words from ws[4096] covering counts+loss+pk

__device__ __forceinline__ void gload16(const void* g, void* l) {
  __builtin_amdgcn_global_load_lds(
      (const __attribute__((address_space(1))) unsigned int*)g,
      (__attribute__((address_space(3))) unsigned int*)l, 16, 0, 0);
}

// ---- codebook prep: zero ws counters, norms, fragment-linear h/l split ----
// 128 blocks (one per 32-col tile) x 256 threads. t -> (col = t>>3, j = t&7).
__global__ __launch_bounds__(256)
void cb_prep_k(const float* __restrict__ cb, float* __restrict__ ws) {
  const int t = threadIdx.x, tile = blockIdx.x;
  // fused zeroing of counts + loss + pk
  for (int i = tile * 256 + t; i < ZERO_W; i += 128 * 256) ws[KCB + i] = 0.0f;

  const int col = t >> 3, j = t & 7;
  const int c0  = tile * 32;
  ushort* tb = (ushort*)((char*)ws + CBF_OFF) + (size_t)tile * 16384;
  const float* src = cb + (size_t)(c0 + col) * DIM;
  float s = 0.0f;
  #pragma unroll
  for (int ks = 0; ks < 16; ++ks) {
    #pragma unroll
    for (int kh = 0; kh < 2; ++kh) {
      float x = src[ks * 16 + kh * 8 + j];
      s += x * x;
      unsigned xb = __float_as_uint(x);
      unsigned hb = xb & 0xFFFF0000u;
      float lf = x - __uint_as_float(hb);   // exact
      tb[ks * 512 + kh * 256 + t]        = (ushort)(xb >> 16);
      tb[8192 + ks * 512 + kh * 256 + t] = (ushort)(__float_as_uint(lf) >> 16);
    }
  }
  s += __shfl_down(s, 4, 8);
  s += __shfl_down(s, 2, 8);
  s += __shfl_down(s, 1, 8);
  if (j == 0) ws[c0 + col] = s;
}

// ---------------- main MFMA kernel ----------------
// 256 blocks x 512 threads (8 waves). Block = 256 rows x 1024 cols
// (mb = blockIdx>>2, cq = blockIdx&3). A (ze rows, bf16 h/l) register-resident:
// wave w owns rows m0 + w*32 .. +31 (128 VGPR of frags). B staged to LDS via
// global_load_lds (16B), double-buffered 2x32KB, SHARED by all 8 waves.
// Inner loop: 2 ds_read_b128 + 3 MFMA per ks, zero VALU.
#define AP 260   // A-stage pitch (floats): 4-float pad -> 16B-aligned, 2-way-only banks

__global__ __launch_bounds__(512, 2)
void vq_mfma_k(const float* __restrict__ ze, float* __restrict__ ws) {
  __shared__ __align__(16) char ldsU[66560];   // max(A-stage 64x260x4, B 2x32KB)

  const int t    = threadIdx.x;
  const int lane = t & 63;
  const int w    = t >> 6;
  const int ln31 = lane & 31;
  const int hl   = lane >> 5;
  const int mb   = blockIdx.x >> 2;
  const int cq   = blockIdx.x & 3;
  const int m0   = mb * 256;

  const float* cbn = ws;
  unsigned long long* pk = (unsigned long long*)((char*)ws + PK_OFF);
  const char* cbF = (const char*)ws + CBF_OFF;

  // ---- A into registers: 4 chunks of 64 rows staged fp32 through LDS ----
  s8v ah[16], al[16];
  float* Af = (float*)ldsU;
  for (int c = 0; c < 4; ++c) {
    __syncthreads();
    {
      int r  = t >> 3;          // 0..63
      int f0 = t & 7;
      const float* src = ze + (size_t)(m0 + c * 64 + r) * DIM;
      #pragma unroll
      for (int i = 0; i < 8; ++i) {
        int f = f0 + 8 * i;
        *(float4*)&Af[r * AP + f * 4] = *(const float4*)(src + f * 4);
      }
    }
    __syncthreads();
    if ((w >> 1) == c) {
      int rl = (w & 1) * 32 + ln31;
      #pragma unroll
      for (int ks = 0; ks < 16; ++ks) {
        float4 x0 = *(const float4*)&Af[rl * AP + ks * 16 + hl * 8];
        float4 x1 = *(const float4*)&Af[rl * AP + ks * 16 + hl * 8 + 4];
        float xs[8] = {x0.x, x0.y, x0.z, x0.w, x1.x, x1.y, x1.z, x1.w};
        #pragma unroll
        for (int j = 0; j < 8; ++j) {
          unsigned xb = __float_as_uint(xs[j]);
          unsigned hb = xb & 0xFFFF0000u;
          float lf = xs[j] - __uint_as_float(hb);
          ah[ks][j] = (short)(xb >> 16);
          al[ks][j] = (short)(__float_as_uint(lf) >> 16);
        }
      }
    }
  }
  __syncthreads();   // A-region reads done before B staging overwrites ldsU

  char* bufs0 = ldsU;
  char* bufs1 = ldsU + 32768;
  const char* qbase = cbF + (size_t)cq * 32 * 32768;

  // issue tile 0 (4 x 1KB per wave = 32KB total)
  {
    const char* g = qbase + (size_t)w * 4096 + (size_t)lane * 16;
    char* lp = bufs0 + w * 4096;
    #pragma unroll
    for (int ii = 0; ii < 4; ++ii) gload16(g + ii * 1024, lp + ii * 1024);
  }

  float best[16];
  int   bidx[16];
  #pragma unroll
  for (int r = 0; r < 16; ++r) { best[r] = -1e30f; bidx[r] = 0; }

  #pragma unroll 1
  for (int tt = 0; tt < 32; ++tt) {
    __syncthreads();   // drains vmcnt: buf[tt&1] ready; all reads of buf[(tt+1)&1] done
    if (tt + 1 < 32) {
      const char* g = qbase + (size_t)(tt + 1) * 32768 + (size_t)w * 4096 + (size_t)lane * 16;
      char* lp = ((tt + 1) & 1 ? bufs1 : bufs0) + w * 4096;
      #pragma unroll
      for (int ii = 0; ii < 4; ++ii) gload16(g + ii * 1024, lp + ii * 1024);
    }

    const int   c0      = cq * 1024 + tt * 32;
    const float half_cv = 0.5f * cbn[c0 + ln31];
    const char* bc      = (tt & 1) ? bufs1 : bufs0;

    f16v hh, xx;
    #pragma unroll
    for (int r = 0; r < 16; ++r) { hh[r] = 0.0f; xx[r] = 0.0f; }

    #pragma unroll
    for (int ks = 0; ks < 16; ++ks) {
      s8v bh = *(const s8v*)(bc + ks * 1024 + lane * 16);
      s8v bl = *(const s8v*)(bc + 16384 + ks * 1024 + lane * 16);
      hh = __builtin_amdgcn_mfma_f32_32x32x16_bf16(ah[ks], bh, hh, 0, 0, 0);
      xx = __builtin_amdgcn_mfma_f32_32x32x16_bf16(ah[ks], bl, xx, 0, 0, 0);
      xx = __builtin_amdgcn_mfma_f32_32x32x16_bf16(al[ks], bh, xx, 0, 0, 0);
    }

    // score = dot - 0.5||e||^2 ; cols ascend with tt => '>' keeps first min
    #pragma unroll
    for (int r = 0; r < 16; ++r) {
      float s = hh[r] + xx[r] - half_cv;
      if (s > best[r]) { best[r] = s; bidx[r] = c0 + ln31; }
    }
  }

  // ---- cross-lane argmax over the 32 cols (masks<32 keep hl halves separate),
  // then device-scope packed atomicMax merge across the 4 col-split blocks ----
  #pragma unroll
  for (int r = 0; r < 16; ++r) {
    float s = best[r];
    int   c = bidx[r];
    #pragma unroll
    for (int mk = 1; mk < 32; mk <<= 1) {
      float os = __shfl_xor(s, mk, 64);
      int   oc = __shfl_xor(c, mk, 64);
      if (os > s || (os == s && oc < c)) { s = os; c = oc; }
    }
    if (ln31 == 0) {
      int row = m0 + w * 32 + (r & 3) + 8 * (r >> 2) + 4 * hl;
      unsigned u = __float_as_uint(s);
      unsigned enc = (u & 0x80000000u) ? ~u : (u | 0x80000000u);
      unsigned long long p = ((unsigned long long)enc << 32) | (unsigned)(KCB - 1 - c);
      atomicMax(&pk[row], p);
    }
  }
}

// ---- gather: indices out, counts, zq, loss partials ----
__global__ __launch_bounds__(256)
void gather_k(const float* __restrict__ ze, const float* __restrict__ cb,
              float* __restrict__ ws, float* __restrict__ out) {
  __shared__ int sIdx[64];
  const int t  = threadIdx.x;
  const int m0 = blockIdx.x * 64;
  float* counts   = ws + KCB;
  float* loss_sum = ws + 2 * KCB;
  const unsigned long long* pk = (const unsigned long long*)((const char*)ws + PK_OFF);

  if (t < 64) {
    unsigned long long p = pk[m0 + t];
    int col = KCB - 1 - (int)(unsigned)(p & 0xFFFFFFFFull);
    out[m0 + t] = (float)col;
    sIdx[t] = col;
    atomicAdd(&counts[col], 1.0f);
  }
  __syncthreads();

  float* out_zq = out + N_TOT;
  const int w = t >> 6, ln = t & 63;
  float lsum = 0.0f;
  #pragma unroll
  for (int p = 0; p < 16; ++p) {
    int r = w + 4 * p;
    float4 cvv = *(const float4*)(cb + (size_t)sIdx[r] * DIM + ln * 4);
    float4 zv  = *(const float4*)(ze + (size_t)(m0 + r) * DIM + ln * 4);
    *(float4*)(out_zq + (size_t)(m0 + r) * DIM + ln * 4) = cvv;
    float dx = cvv.x - zv.x, dy = cvv.y - zv.y, dz = cvv.z - zv.z, dw = cvv.w - zv.w;
    lsum += dx * dx + dy * dy + dz * dz + dw * dw;
  }
  #pragma unroll
  for (int off = 32; off > 0; off >>= 1) lsum += __shfl_down(lsum, off, 64);
  if (ln == 0) atomicAdd(loss_sum, lsum);
}

// ---------------- fallback (round-1 fp32 path, if ws too small) ----------------
__global__ void zero_ws_k(float* __restrict__ ws, int nw) {
  int i = blockIdx.x * 256 + threadIdx.x;
  if (i < nw) ws[KCB + i] = 0.0f;
}

__global__ void cbnorm_k(const float* __restrict__ cb, float* __restrict__ ws) {
  int row  = blockIdx.x * 4 + (threadIdx.x >> 6);
  int lane = threadIdx.x & 63;
  float4 v = *(const float4*)(cb + (size_t)row * DIM + lane * 4);
  float s = v.x*v.x + v.y*v.y + v.z*v.z + v.w*v.w;
  #pragma unroll
  for (int off = 32; off > 0; off >>= 1) s += __shfl_down(s, off, 64);
  if (lane == 0) ws[row] = s;
}

#define FBM 32
#define FBN 64
#define FBD 128
__global__ __launch_bounds__(256, 4)
void vq_main_k(const float* __restrict__ ze, const float* __restrict__ cb,
               float* __restrict__ ws, float* __restrict__ out) {
  __shared__ float As[FBM * FBD];
  __shared__ float Bs[FBN * FBD];
  __shared__ float red_d[FBM * 16];
  __shared__ int   red_i[FBM * 16];
  __shared__ int   sIdx[FBM];

  const int t  = threadIdx.x;
  const int tx = t & 15;
  const int ty = t >> 4;
  const int m0 = blockIdx.x * FBM;

  const float* cbn = ws;
  float* counts    = ws + KCB;
  float* loss_sum  = ws + 2 * KCB;

  float best0 = 1e30f, best1 = 1e30f;
  int   bidx0 = 0,     bidx1 = 0;
  const int sA = ty & 7;
  const int sB = tx & 7;

  for (int kt = 0; kt < KCB / FBN; ++kt) {
    float cbnj[4];
    #pragma unroll
    for (int j = 0; j < 4; ++j) cbnj[j] = cbn[kt * FBN + tx + 16 * j];
    float acc[2][4];
    #pragma unroll
    for (int i = 0; i < 2; ++i)
      #pragma unroll
      for (int j = 0; j < 4; ++j) acc[i][j] = 0.0f;

    for (int dc = 0; dc < DIM / FBD; ++dc) {
      __syncthreads();
      {
        int c  = t & 31;
        int rb = t >> 5;
        #pragma unroll
        for (int p = 0; p < 4; ++p) {
          int r = rb + 8 * p;
          float4 v = *(const float4*)(ze + (size_t)(m0 + r) * DIM + dc * FBD + c * 4);
          *(float4*)&As[r * FBD + ((c ^ (r & 7)) << 2)] = v;
        }
        #pragma unroll
        for (int p = 0; p < 8; ++p) {
          int r = rb + 8 * p;
          float4 v = *(const float4*)(cb + (size_t)(kt * FBN + r) * DIM + dc * FBD + c * 4);
          *(float4*)&Bs[r * FBD + ((c ^ (r & 7)) << 2)] = v;
        }
      }
      __syncthreads();
      #pragma unroll 8
      for (int ds = 0; ds < FBD / 4; ++ds) {
        float4 a0 = *(const float4*)&As[ty * FBD + ((ds ^ sA) << 2)];
        float4 a1 = *(const float4*)&As[(ty + 16) * FBD + ((ds ^ sA) << 2)];
        float4 b[4];
        #pragma unroll
        for (int j = 0; j < 4; ++j)
          b[j] = *(const float4*)&Bs[(tx + 16 * j) * FBD + ((ds ^ sB) << 2)];
        #pragma unroll
        for (int j = 0; j < 4; ++j) {
          acc[0][j] = fmaf(a0.x, b[j].x, acc[0][j]);
          acc[0][j] = fmaf(a0.y, b[j].y, acc[0][j]);
          acc[0][j] = fmaf(a0.z, b[j].z, acc[0][j]);
          acc[0][j] = fmaf(a0.w, b[j].w, acc[0][j]);
          acc[1][j] = fmaf(a1.x, b[j].x, acc[1][j]);
          acc[1][j] = fmaf(a1.y, b[j].y, acc[1][j]);
          acc[1][j] = fmaf(a1.z, b[j].z, acc[1][j]);
          acc[1][j] = fmaf(a1.w, b[j].w, acc[1][j]);
        }
      }
    }
    #pragma unroll
    for (int j = 0; j < 4; ++j) {
      int kg = kt * FBN + tx + 16 * j;
      float d0 = cbnj[j] - 2.0f * acc[0][j];
      float d1 = cbnj[j] - 2.0f * acc[1][j];
      if (d0 < best0) { best0 = d0; bidx0 = kg; }
      if (d1 < best1) { best1 = d1; bidx1 = kg; }
    }
  }

  __syncthreads();
  red_d[ty * 16 + tx] = best0;        red_i[ty * 16 + tx] = bidx0;
  red_d[(ty + 16) * 16 + tx] = best1; red_i[(ty + 16) * 16 + tx] = bidx1;
  __syncthreads();

  if (t < FBM) {
    float bd = red_d[t * 16]; int bi = red_i[t * 16];
    #pragma unroll
    for (int q = 1; q < 16; ++q) {
      float d = red_d[t * 16 + q]; int i2 = red_i[t * 16 + q];
      if (d < bd || (d == bd && i2 < bi)) { bd = d; bi = i2; }
    }
    out[m0 + t] = (float)bi;
    sIdx[t] = bi;
    atomicAdd(&counts[bi], 1.0f);
  }
  __syncthreads();

  float* out_zq = out + N_TOT;
  const int wv = t >> 6, ln = t & 63;
  float lsum = 0.0f;
  #pragma unroll
  for (int p = 0; p < 8; ++p) {
    int r = wv + 4 * p;
    float4 cvv = *(const float4*)(cb + (size_t)sIdx[r] * DIM + ln * 4);
    float4 zv  = *(const float4*)(ze + (size_t)(m0 + r) * DIM + ln * 4);
    *(float4*)(out_zq + (size_t)(m0 + r) * DIM + ln * 4) = cvv;
    float dx = cvv.x - zv.x, dy = cvv.y - zv.y, dz = cvv.z - zv.z, dw = cvv.w - zv.w;
    lsum += dx*dx + dy*dy + dz*dz + dw*dw;
  }
  #pragma unroll
  for (int off = 32; off > 0; off >>= 1) lsum += __shfl_down(lsum, off, 64);
  if (ln == 0) atomicAdd(loss_sum, lsum);
}

__global__ void finalize_k(const float* __restrict__ ws, float* __restrict__ out) {
  __shared__ float red[256];
  int t = threadIdx.x;
  const float* counts = ws + KCB;
  float s = 0.0f;
  for (int k = t; k < KCB; k += 256) {
    float p = counts[k] * 0.1f;
    s += p * logf(p + 1e-10f);
  }
  red[t] = s;
  __syncthreads();
  for (int q = 128; q > 0; q >>= 1) { if (t < q) red[t] += red[t + q]; __syncthreads(); }
  if (t == 0) {
    float loss = ws[2 * KCB] / (float)((size_t)N_TOT * DIM);
    float* o = out + N_TOT + (size_t)N_TOT * DIM;
    o[0] = loss;
    o[1] = loss;
    o[2] = expf(-red[0]);
  }
}

extern "C" void kernel_launch(void* const* d_in, const int* in_sizes, int n_in,
                              void* d_out, int out_size, void* d_ws, size_t ws_size,
                              hipStream_t stream) {
  const float* ze = (const float*)d_in[0];
  const float* cb = (const float*)d_in[1];
  float* out = (float*)d_out;
  float* ws  = (float*)d_ws;

  if (ws_size >= WS_NEED) {
    cb_prep_k<<<128, 256, 0, stream>>>(cb, ws);
    vq_mfma_k<<<256, 512, 0, stream>>>(ze, ws);
    gather_k<<<N_TOT / 64, 256, 0, stream>>>(ze, cb, ws, out);
  } else {
    zero_ws_k<<<(KCB + 1 + 255) / 256, 256, 0, stream>>>(ws, KCB + 1);
    cbnorm_k<<<KCB / 4, 256, 0, stream>>>(cb, ws);
    vq_main_k<<<N_TOT / FBM, 256, 0, stream>>>(ze, cb, ws, out);
  }
  finalize_k<<<1, 256, 0, stream>>>(ws, out);
}